// Round 2
// baseline (1121.654 us; speedup 1.0000x reference)
//
#include <hip/hip_runtime.h>

// Cost volume: out[b,d,h,w] = (w>=d) ? (1/32) * sum_c L[b,c,h,w]*R[b,c,h,w-d] : 0
// B=4, C=32, H=256, W=512, D=64, fp32.
//
// R2: occupancy + latency attack.
//  - 2 blocks per (b,h) row, each covers 32 of the 64 disparities.
//  - Thread tile WT=4 x DT=8 -> 32 accs, ~60 VGPR, launch_bounds(512,8) -> 8 waves/SIMD.
//  - R staged in LDS in 2 channel chunks of 16 (36 KB) -> 4 blocks/CU -> 32 waves/CU.
//  - Staging via async global_load_lds width=16 (no VGPR round trip).
//  - L prefetched one c-iteration ahead.

constexpr int Bn = 4, Cn = 32, Hn = 256, Wn = 512, Dn = 64;
constexpr int WT = 4, DT = 8;
constexpr int PAD = 64;
constexpr int STRIDE = PAD + Wn;     // 576 floats per channel slot
constexpr int CCHUNK = 16;           // channels resident in LDS at a time
constexpr int HW = Hn * Wn;          // 131072

__global__ __launch_bounds__(512, 8)
void cost_volume_kernel(const float* __restrict__ left,
                        const float* __restrict__ right,
                        float* __restrict__ out)
{
    __shared__ __align__(16) float Rs[CCHUNK * STRIDE];   // 36864 B

    const int tid  = threadIdx.x;
    const int bh   = blockIdx.x;
    const int dblk = blockIdx.y;          // 0 or 1: which 32 disparities
    const int b    = bh >> 8;             // H = 256
    const int h    = bh & (Hn - 1);

    const float* Lrow = left  + (b * Cn * Hn + h) * Wn;   // channel stride HW
    const float* Rrow = right + (b * Cn * Hn + h) * Wn;

    // thread tile coords
    const int tw = tid & 127;             // 128 w-groups
    const int td = tid >> 7;              // 4 d-groups of 8
    const int w0 = tw << 2;
    const int d0g = (dblk << 5) + (td << 3);          // global base disparity
    const int rb  = PAD + w0 - d0g - 8;               // window base in LDS row (>=0, mult of 4)

    // --- zero the left pad once (staging never touches [0,PAD))
    if (tid < 256) {
        const int c  = tid >> 4;                       // 0..15
        const int wq = (tid & 15) << 2;                // 0..60
        *reinterpret_cast<float4*>(&Rs[c * STRIDE + wq]) =
            make_float4(0.f, 0.f, 0.f, 0.f);
    }

    // --- async stage of one 16-channel chunk: 2048 float4, 4 per thread
    auto stage = [&](int cbase) {
        const float* gsrc = Rrow + cbase * HW;
        #pragma unroll
        for (int k = 0; k < 4; ++k) {
            const int f = tid + (k << 9);              // float4 index 0..2047
            const int c = f >> 7;                      // local channel 0..15
            const int w = (f & 127) << 2;
            const float* g = gsrc + c * HW + w;
            float* l = &Rs[c * STRIDE + PAD + w];
            __builtin_amdgcn_global_load_lds(
                (const __attribute__((address_space(1))) float*)g,
                (__attribute__((address_space(3))) float*)l, 16, 0, 0);
        }
    };

    float acc[DT][WT];
    #pragma unroll
    for (int j = 0; j < DT; ++j)
        #pragma unroll
        for (int i = 0; i < WT; ++i)
            acc[j][i] = 0.f;

    stage(0);
    float4 Lv = *reinterpret_cast<const float4*>(&Lrow[w0]);   // c = 0
    __syncthreads();

    // acc[j][i] += L[c][w0+i] * R[c][w0+i-(d0g+j)] -> Rs[c*STRIDE + rb + 8+i-j]
    #pragma unroll 1
    for (int cc = 0; cc < Cn; cc += CCHUNK) {
        if (cc) {
            __syncthreads();                            // compute on prev chunk done
            stage(cc);
            __syncthreads();
        }
        #pragma unroll
        for (int cl = 0; cl < CCHUNK; ++cl) {
            const int c = cc + cl;
            // prefetch next L (global channel index; independent of LDS chunk)
            float4 Ln = Lv;
            if (c + 1 < Cn)
                Ln = *reinterpret_cast<const float4*>(&Lrow[(c + 1) * HW + w0]);

            const float* rp = &Rs[cl * STRIDE + rb];
            float r[12];                                // window, r[1..11] used
            #pragma unroll
            for (int q = 0; q < 3; ++q)
                *reinterpret_cast<float4*>(&r[q * 4]) =
                    *reinterpret_cast<const float4*>(&rp[q * 4]);

            const float lv[4] = {Lv.x, Lv.y, Lv.z, Lv.w};
            #pragma unroll
            for (int j = 0; j < DT; ++j)
                #pragma unroll
                for (int i = 0; i < WT; ++i)
                    acc[j][i] = fmaf(lv[i], r[8 + i - j], acc[j][i]);

            Lv = Ln;
        }
    }

    // --- epilogue: out[b][d0g+j][h][w0..w0+3]
    constexpr float inv = 1.0f / 32.0f;
    float* op = out + ((b * Dn + d0g) * Hn + h) * Wn + w0;
    #pragma unroll
    for (int j = 0; j < DT; ++j) {
        const float4 v = make_float4(acc[j][0] * inv, acc[j][1] * inv,
                                     acc[j][2] * inv, acc[j][3] * inv);
        *reinterpret_cast<float4*>(&op[j * HW]) = v;
    }
}

extern "C" void kernel_launch(void* const* d_in, const int* in_sizes, int n_in,
                              void* d_out, int out_size, void* d_ws, size_t ws_size,
                              hipStream_t stream) {
    const float* left  = (const float*)d_in[0];
    const float* right = (const float*)d_in[1];
    float* out = (float*)d_out;
    cost_volume_kernel<<<dim3(Bn * Hn, 2), dim3(512), 0, stream>>>(left, right, out);
}

// Round 3
// 707.409 us; speedup vs baseline: 1.5856x; 1.5856x over previous
//
#include <hip/hip_runtime.h>

// Cost volume: out[b,d,h,w] = (w>=d) ? (1/32) * sum_c L[b,c,h,w]*R[b,c,h,w-d] : 0
// B=4, C=32, H=256, W=512, D=64, fp32.
//
// R3: R2's occupancy plan with the spill fixed.
//  - 2 blocks per (b,h) row (d split 32/32), thread tile WT=4 x DT=8 (32 accs).
//  - R staged in LDS in 2 chunks of 16 channels (36 KB) -> 4 blocks/CU.
//  - __launch_bounds__(512,4): 128-VGPR cap. R2's (512,8) forced 32 VGPRs and
//    spilled acc[] to scratch (WRITE_SIZE 131MB -> 2.24GB). Never cap below
//    ~70 VGPR here.
//  - Staging via async global_load_lds width=16; L prefetched 1 c ahead.

constexpr int Bn = 4, Cn = 32, Hn = 256, Wn = 512, Dn = 64;
constexpr int WT = 4, DT = 8;
constexpr int PAD = 64;
constexpr int STRIDE = PAD + Wn;     // 576 floats per channel slot
constexpr int CCHUNK = 16;           // channels resident in LDS at a time
constexpr int HW = Hn * Wn;          // 131072

__global__ __launch_bounds__(512, 4)
void cost_volume_kernel(const float* __restrict__ left,
                        const float* __restrict__ right,
                        float* __restrict__ out)
{
    __shared__ __align__(16) float Rs[CCHUNK * STRIDE];   // 36864 B

    const int tid  = threadIdx.x;
    const int bh   = blockIdx.x;
    const int dblk = blockIdx.y;          // 0 or 1: which 32 disparities
    const int b    = bh >> 8;             // H = 256
    const int h    = bh & (Hn - 1);

    const float* Lrow = left  + (b * Cn * Hn + h) * Wn;   // channel stride HW
    const float* Rrow = right + (b * Cn * Hn + h) * Wn;

    // thread tile coords
    const int tw = tid & 127;             // 128 w-groups
    const int td = tid >> 7;              // 4 d-groups of 8
    const int w0 = tw << 2;
    const int d0g = (dblk << 5) + (td << 3);          // global base disparity
    const int rb  = PAD + w0 - d0g - 8;               // window base (>=0, mult of 4)

    // --- zero the left pad once (staging never touches [0,PAD))
    if (tid < 256) {
        const int c  = tid >> 4;                       // 0..15
        const int wq = (tid & 15) << 2;                // 0..60
        *reinterpret_cast<float4*>(&Rs[c * STRIDE + wq]) =
            make_float4(0.f, 0.f, 0.f, 0.f);
    }

    // --- async stage of one 16-channel chunk: 2048 float4, 4 per thread.
    // Within a wave: f spans 64 consecutive float4 -> same local channel,
    // contiguous LDS dest = the required wave-uniform-base + lane*16 pattern.
    auto stage = [&](int cbase) {
        const float* gsrc = Rrow + cbase * HW;
        #pragma unroll
        for (int k = 0; k < 4; ++k) {
            const int f = tid + (k << 9);              // float4 index 0..2047
            const int c = f >> 7;                      // local channel 0..15
            const int w = (f & 127) << 2;
            const float* g = gsrc + c * HW + w;
            float* l = &Rs[c * STRIDE + PAD + w];
            __builtin_amdgcn_global_load_lds(
                (const __attribute__((address_space(1))) float*)g,
                (__attribute__((address_space(3))) float*)l, 16, 0, 0);
        }
    };

    stage(0);

    float acc[DT][WT];
    #pragma unroll
    for (int j = 0; j < DT; ++j)
        #pragma unroll
        for (int i = 0; i < WT; ++i)
            acc[j][i] = 0.f;

    float4 Lv = *reinterpret_cast<const float4*>(&Lrow[w0]);   // c = 0
    __syncthreads();

    // acc[j][i] += L[c][w0+i] * R[c][w0+i-(d0g+j)] -> Rs[c*STRIDE + rb + 8+i-j]
    #pragma unroll 1
    for (int cc = 0; cc < Cn; cc += CCHUNK) {
        if (cc) {
            __syncthreads();                            // all waves done with prev chunk
            stage(cc);
            __syncthreads();                            // staging drained (vmcnt0+barrier)
        }
        #pragma unroll
        for (int cl = 0; cl < CCHUNK; ++cl) {
            const int c = cc + cl;
            float4 Ln = Lv;                             // prefetch next L
            if (c + 1 < Cn)
                Ln = *reinterpret_cast<const float4*>(&Lrow[(c + 1) * HW + w0]);

            const float* rp = &Rs[cl * STRIDE + rb];
            float r[12];                                // r[1..11] used
            #pragma unroll
            for (int q = 0; q < 3; ++q)
                *reinterpret_cast<float4*>(&r[q * 4]) =
                    *reinterpret_cast<const float4*>(&rp[q * 4]);

            const float lv[4] = {Lv.x, Lv.y, Lv.z, Lv.w};
            #pragma unroll
            for (int j = 0; j < DT; ++j)
                #pragma unroll
                for (int i = 0; i < WT; ++i)
                    acc[j][i] = fmaf(lv[i], r[8 + i - j], acc[j][i]);

            Lv = Ln;
        }
    }

    // --- epilogue: out[b][d0g+j][h][w0..w0+3]
    constexpr float inv = 1.0f / 32.0f;
    float* op = out + ((b * Dn + d0g) * Hn + h) * Wn + w0;
    #pragma unroll
    for (int j = 0; j < DT; ++j) {
        const float4 v = make_float4(acc[j][0] * inv, acc[j][1] * inv,
                                     acc[j][2] * inv, acc[j][3] * inv);
        *reinterpret_cast<float4*>(&op[j * HW]) = v;
    }
}

extern "C" void kernel_launch(void* const* d_in, const int* in_sizes, int n_in,
                              void* d_out, int out_size, void* d_ws, size_t ws_size,
                              hipStream_t stream) {
    const float* left  = (const float*)d_in[0];
    const float* right = (const float*)d_in[1];
    float* out = (float*)d_out;
    cost_volume_kernel<<<dim3(Bn * Hn, 2), dim3(512), 0, stream>>>(left, right, out);
}